// Round 1
// baseline (642.455 us; speedup 1.0000x reference)
//
#include <hip/hip_runtime.h>

#define B_  4
#define N_  4096
#define K_  32
#define C_  64
#define D1_ 64
#define D2_ 64
#define DH_ 128

// ---------------------------------------------------------------------------
// Kernel 0: one-shot transforms.
//  - copy xyz (output 0 of the tuple) into d_out[0 .. B*N*3)
//  - W_gvT[c][o] = W_gv[o][c]   (64x64)
//  - W_hT [i][o] = W_h [o][i]   (128x128)
// total elements = 49152 + 4096 + 16384 = 69632 = 272 * 256 exactly.
// ---------------------------------------------------------------------------
__global__ __launch_bounds__(256) void k_transforms(
    const float* __restrict__ xyz,
    const float* __restrict__ W_gv,
    const float* __restrict__ W_h,
    float* __restrict__ out_xyz,
    float* __restrict__ W_gvT,
    float* __restrict__ W_hT)
{
    int e = blockIdx.x * 256 + threadIdx.x;
    if (e < B_*N_*3) { out_xyz[e] = xyz[e]; return; }
    e -= B_*N_*3;
    if (e < D2_*C_) { int o = e >> 6, c = e & 63; W_gvT[c*D2_ + o] = W_gv[e]; return; }
    e -= D2_*C_;
    if (e < DH_*(D1_+D2_)) { int o = e >> 7, i = e & 127; W_hT[i*DH_ + o] = W_h[e]; }
}

// ---------------------------------------------------------------------------
// Kernel 1: Pgv[b,n,o] = sum_c features[b][c][n] * W_gv[o][c]
// One block per (b, 64-point tile). features loaded coalesced along n into an
// LDS tile, then a register-tiled 64x64x64 mini-GEMM (2n x 8o per thread).
// ---------------------------------------------------------------------------
__global__ __launch_bounds__(256) void k_pre(
    const float* __restrict__ features,
    const float* __restrict__ W_gvT,
    float* __restrict__ Pgv)
{
    const int b  = blockIdx.x >> 6;
    const int n0 = (blockIdx.x & 63) * 64;
    const int t  = threadIdx.x;

    __shared__ __align__(16) float ftile[64 * 66];   // [c][n_loc], stride 66

    const int nn = t & 63, cq = t >> 6;
#pragma unroll
    for (int r = 0; r < 16; r++) {
        int c = cq * 16 + r;
        ftile[c*66 + nn] = features[(b*C_ + c)*N_ + n0 + nn];
    }
    __syncthreads();

    const int nt = t & 31, ot = t >> 5;      // 32 n-tiles x 8 o-tiles
    const int nl0 = nt * 2, o0 = ot * 8;
    float acc[2][8] = {};
    for (int c = 0; c < 64; c++) {
        float a0 = ftile[c*66 + nl0];
        float a1 = ftile[c*66 + nl0 + 1];
        float w[8];
        *(float4*)&w[0] = *(const float4*)&W_gvT[c*64 + o0];
        *(float4*)&w[4] = *(const float4*)&W_gvT[c*64 + o0 + 4];
#pragma unroll
        for (int oo = 0; oo < 8; oo++) {
            acc[0][oo] = fmaf(a0, w[oo], acc[0][oo]);
            acc[1][oo] = fmaf(a1, w[oo], acc[1][oo]);
        }
    }
#pragma unroll
    for (int kk = 0; kk < 2; kk++) {
        int n = n0 + nl0 + kk;
        float* dst = &Pgv[(b*N_ + n)*64 + o0];
        *(float4*)&dst[0] = make_float4(acc[kk][0], acc[kk][1], acc[kk][2], acc[kk][3]);
        *(float4*)&dst[4] = make_float4(acc[kk][4], acc[kk][5], acc[kk][6], acc[kk][7]);
    }
}

// ---------------------------------------------------------------------------
// Kernel 2: main fused kernel. One block (256 threads) per (b,n) point.
//  phase 1: build fuseT[i][k] (i = 0..127 = gu|gv concat, k = 0..31 neighbors)
//           gu  = relu((cen_gu[o] + xyz[j].W_gu[o][3:6]) * s + b)
//           gv  = relu((Pgv[n][o] + Pgv[j][o])           * s + b)
//  phase 2: h GEMM  M=32(k) N=128(o) Kdim=128(i); 2k x 8o register tile;
//           relu + k-sum via shfl_xor (all 32 k live in one wave per o-range)
//  phase 3: f layer (64 outputs), + residual, transposed store.
// ---------------------------------------------------------------------------
__global__ __launch_bounds__(256) void k_main(
    const float* __restrict__ xyz,
    const float* __restrict__ features,
    const int*   __restrict__ idx,
    const float* __restrict__ W_gu,
    const float* __restrict__ s_gu, const float* __restrict__ b_gu,
    const float* __restrict__ Pgv,
    const float* __restrict__ s_gv, const float* __restrict__ b_gv,
    const float* __restrict__ W_hT,
    const float* __restrict__ s_h,  const float* __restrict__ b_h,
    const float* __restrict__ W_f,
    const float* __restrict__ s_f,  const float* __restrict__ b_f,
    float* __restrict__ outF)
{
    const int bid = blockIdx.x;
    const int b = bid >> 12;          // N_ = 4096 = 2^12
    const int n = bid & (N_ - 1);
    const int t = threadIdx.x;

    __shared__ float cen_gv[64];
    __shared__ float cen_gu[64];
    __shared__ int   idx_s[K_];
    __shared__ __align__(16) float fuseT[128 * 36];   // [i][k], stride 36
    __shared__ __align__(16) float pooled[128];

    if (t < 64) {
        cen_gv[t] = Pgv[bid*64 + t];
        const float* xp = &xyz[bid*3];
        cen_gu[t] = xp[0]*W_gu[t*6+0] + xp[1]*W_gu[t*6+1] + xp[2]*W_gu[t*6+2];
    } else if (t >= 128 && t < 128 + K_) {
        idx_s[t - 128] = idx[n*K_ + (t - 128)];
    }
    __syncthreads();

    // -------- phase 1: build fuse (2048 elements: 32 k x 64 o) --------
    for (int e = t; e < K_*64; e += 256) {
        const int o = e & 63;
        const int k = e >> 6;
        const int jb = (b << 12) | idx_s[k];        // b*N_ + j
        // gu (rows 0..63): neighbor xyz half
        const float* xj = &xyz[jb*3];               // wave-uniform per k-group
        float gun = xj[0]*W_gu[o*6+3] + xj[1]*W_gu[o*6+4] + xj[2]*W_gu[o*6+5];
        float gu  = (cen_gu[o] + gun) * s_gu[o] + b_gu[o];
        fuseT[o*36 + k] = fmaxf(gu, 0.f);
        // gv (rows 64..127)
        float gv = (cen_gv[o] + Pgv[jb*64 + o]) * s_gv[o] + b_gv[o];
        fuseT[(64 + o)*36 + k] = fmaxf(gv, 0.f);
    }
    __syncthreads();

    // -------- phase 2: h GEMM + pooled --------
    const int kt = t & 15, ot = t >> 4;     // 16 k-tiles x 16 o-tiles
    const int k0 = kt * 2, o0 = ot * 8;
    float acc[2][8] = {};
#pragma unroll 2
    for (int i = 0; i < 128; i++) {
        float2 a = *(const float2*)&fuseT[i*36 + k0];
        float w[8];
        *(float4*)&w[0] = *(const float4*)&W_hT[i*128 + o0];
        *(float4*)&w[4] = *(const float4*)&W_hT[i*128 + o0 + 4];
#pragma unroll
        for (int oo = 0; oo < 8; oo++) {
            acc[0][oo] = fmaf(a.x, w[oo], acc[0][oo]);
            acc[1][oo] = fmaf(a.y, w[oo], acc[1][oo]);
        }
    }
#pragma unroll
    for (int oo = 0; oo < 8; oo++) {
        const int o = o0 + oo;
        const float s = s_h[o], bb = b_h[o];
        float v = fmaxf(acc[0][oo]*s + bb, 0.f) + fmaxf(acc[1][oo]*s + bb, 0.f);
        // reduce across the 16 kt lanes (covers all 32 k)
        v += __shfl_xor(v, 1);
        v += __shfl_xor(v, 2);
        v += __shfl_xor(v, 4);
        v += __shfl_xor(v, 8);
        if (kt == 0) pooled[o] = v;       // sum over k; /K applied in phase 3
    }
    __syncthreads();

    // -------- phase 3: f layer + residual, transposed store --------
    if (t < 64) {
        const int c = t;
        float a2 = 0.f;
#pragma unroll
        for (int i0 = 0; i0 < 128; i0 += 4) {
            float4 p = *(const float4*)&pooled[i0];
            float4 w = *(const float4*)&W_f[c*128 + i0];
            a2 += p.x*w.x + p.y*w.y + p.z*w.z + p.w*w.w;
        }
        a2 *= (1.f / (float)K_);
        float v = fmaxf(a2*s_f[c] + b_f[c], 0.f);
        outF[(b*C_ + c)*N_ + n] = v + features[(b*C_ + c)*N_ + n];
    }
}

// ---------------------------------------------------------------------------
extern "C" void kernel_launch(void* const* d_in, const int* in_sizes, int n_in,
                              void* d_out, int out_size, void* d_ws, size_t ws_size,
                              hipStream_t stream)
{
    const float* xyz      = (const float*)d_in[0];
    const float* features = (const float*)d_in[1];
    const int*   idx      = (const int*)  d_in[2];
    const float* W_gu     = (const float*)d_in[3];
    const float* s_gu     = (const float*)d_in[4];
    const float* b_gu     = (const float*)d_in[5];
    const float* W_gv     = (const float*)d_in[6];
    const float* s_gv     = (const float*)d_in[7];
    const float* b_gv     = (const float*)d_in[8];
    const float* W_h      = (const float*)d_in[9];
    const float* s_h      = (const float*)d_in[10];
    const float* b_h      = (const float*)d_in[11];
    const float* W_f      = (const float*)d_in[12];
    const float* s_f      = (const float*)d_in[13];
    const float* b_f      = (const float*)d_in[14];

    float* out  = (float*)d_out;          // tuple: xyz first, then out
    float* outF = out + B_*N_*3;

    // workspace: Pgv (4 MB) + W_gvT (16 KB) + W_hT (64 KB) = ~4.28 MB
    float* ws    = (float*)d_ws;
    float* Pgv   = ws;                       // B*N*64 = 1048576 floats
    float* W_gvT = ws + (size_t)B_*N_*64;    // 4096 floats
    float* W_hT  = W_gvT + D2_*C_;           // 16384 floats

    k_transforms<<<272, 256, 0, stream>>>(xyz, W_gv, W_h, out, W_gvT, W_hT);
    k_pre<<<B_*(N_/64), 256, 0, stream>>>(features, W_gvT, Pgv);
    k_main<<<B_*N_, 256, 0, stream>>>(xyz, features, idx,
                                      W_gu, s_gu, b_gu,
                                      Pgv, s_gv, b_gv,
                                      W_hT, s_h, b_h,
                                      W_f, s_f, b_f,
                                      outF);
}

// Round 2
// 145.511 us; speedup vs baseline: 4.4152x; 4.4152x over previous
//
#include <hip/hip_runtime.h>

#define B_  4
#define N_  4096
#define K_  32
#define C_  64
#define D1_ 64
#define D2_ 64
#define DH_ 128
#define PPB 8

typedef short  short8   __attribute__((ext_vector_type(8)));
typedef float  floatx16 __attribute__((ext_vector_type(16)));
typedef unsigned short ushort_t;
typedef unsigned int   uint_t;

__device__ __forceinline__ float bf_lo(uint_t u){ union{uint_t i;float f;} x; x.i = u << 16; return x.f; }
__device__ __forceinline__ float bf_hi(uint_t u){ union{uint_t i;float f;} x; x.i = u & 0xffff0000u; return x.f; }
__device__ __forceinline__ uint_t bf_of(float f){ union{float f;uint_t i;} x; x.f = f; uint_t b = x.i; return (b + 0x7fffu + ((b >> 16) & 1u)) >> 16; }  // RNE
__device__ __forceinline__ uint_t bf_pk(float a, float b){ return bf_of(a) | (bf_of(b) << 16); }

// ---------------------------------------------------------------------------
// Kernel 0: one-shot transforms.
//  - copy xyz into d_out[0 .. B*N*3)
//  - W_gvT[c][o] = W_gv[o][c]
//  - Bpack: W_h as bf16 in MFMA B-fragment order:
//      flat = ((w*8+c)*64 + l)*8 + j  ->  W_h[o = w*32+(l&31)][i = c*16+(l>>5)*8+j]
//  - W_fT[i][c] = W_f[c][i]
//  49152 + 4096 + 16384 + 8192 = 77824 = 304*256 exactly.
// ---------------------------------------------------------------------------
__global__ __launch_bounds__(256) void k_transforms(
    const float* __restrict__ xyz,
    const float* __restrict__ W_gv,
    const float* __restrict__ W_h,
    const float* __restrict__ W_f,
    float* __restrict__ out_xyz,
    float* __restrict__ W_gvT,
    ushort_t* __restrict__ Bpack,
    float* __restrict__ W_fT)
{
    int e = blockIdx.x * 256 + threadIdx.x;
    if (e < B_*N_*3) { out_xyz[e] = xyz[e]; return; }
    e -= B_*N_*3;
    if (e < D2_*C_) { int o = e >> 6, c = e & 63; W_gvT[c*D2_ + o] = W_gv[e]; return; }
    e -= D2_*C_;
    if (e < DH_*(D1_+D2_)) {
        int j = e & 7, l = (e >> 3) & 63, c = (e >> 9) & 7, w = e >> 12;
        int o = w*32 + (l & 31);
        int i = c*16 + (l >> 5)*8 + j;
        Bpack[e] = (ushort_t)bf_of(W_h[o*(D1_+D2_) + i]);
        return;
    }
    e -= DH_*(D1_+D2_);
    if (e < C_*DH_) { int i = e >> 6, c = e & 63; W_fT[e] = W_f[c*DH_ + i]; }
}

// ---------------------------------------------------------------------------
// Kernel 1: per-point precompute.
//  Pgv[n][o] = feats[n]·W_gvT  (64x64x64 mini-GEMM, LDS-tiled)
//  q[n][o] = xyz[n]·W_gu[o][0:3],  r[n][o] = xyz[n]·W_gu[o][3:6]
//  Qs  [n][0:64]  = q*s_gu + b_gu          (fp32)   center half (affine folded)
//  Qs  [n][64:128]= Pgv*s_gv + b_gv        (fp32)
//  Pcat[n][0:64]  = r*s_gu                 (bf16)   neighbor half (scale folded)
//  Pcat[n][64:128]= Pgv*s_gv               (bf16)
//  => fuse[k][i] = relu(Qs[n][i] + Pcat[idx[n][k]][i])
// ---------------------------------------------------------------------------
__global__ __launch_bounds__(256) void k_pre(
    const float* __restrict__ xyz,
    const float* __restrict__ features,
    const float* __restrict__ W_gvT,
    const float* __restrict__ W_gu,
    const float* __restrict__ s_gu, const float* __restrict__ b_gu,
    const float* __restrict__ s_gv, const float* __restrict__ b_gv,
    float* __restrict__ Qs,
    ushort_t* __restrict__ Pcat)
{
    const int b  = blockIdx.x >> 6;
    const int n0 = (blockIdx.x & 63) * 64;
    const int t  = threadIdx.x;

    __shared__ __align__(16) float ftile[64 * 66];   // [c][n_loc], stride 66
    __shared__ float xs[192];
    __shared__ float wgu[384];

    const int nn = t & 63, cq = t >> 6;
#pragma unroll
    for (int r = 0; r < 16; r++) {
        int c = cq * 16 + r;
        ftile[c*66 + nn] = features[(b*C_ + c)*N_ + n0 + nn];
    }
    if (t < 192) xs[t] = xyz[(b*N_ + n0)*3 + t];
    if (t < 128) { wgu[t] = W_gu[t]; wgu[t+128] = W_gu[t+128]; wgu[t+256] = W_gu[t+256]; }
    __syncthreads();

    const int nt = t & 31, ot = t >> 5;      // 32 n-tiles x 8 o-tiles
    const int nl0 = nt * 2, o0 = ot * 8;

    float acc[2][8] = {};
    for (int c = 0; c < 64; c++) {
        float a0 = ftile[c*66 + nl0];
        float a1 = ftile[c*66 + nl0 + 1];
        float wv[8];
        *(float4*)&wv[0] = *(const float4*)&W_gvT[c*64 + o0];
        *(float4*)&wv[4] = *(const float4*)&W_gvT[c*64 + o0 + 4];
#pragma unroll
        for (int oo = 0; oo < 8; oo++) {
            acc[0][oo] = fmaf(a0, wv[oo], acc[0][oo]);
            acc[1][oo] = fmaf(a1, wv[oo], acc[1][oo]);
        }
    }

    float sgu[8], bgu[8], sgv[8], bgv[8];
    *(float4*)&sgu[0] = *(const float4*)&s_gu[o0]; *(float4*)&sgu[4] = *(const float4*)&s_gu[o0+4];
    *(float4*)&bgu[0] = *(const float4*)&b_gu[o0]; *(float4*)&bgu[4] = *(const float4*)&b_gu[o0+4];
    *(float4*)&sgv[0] = *(const float4*)&s_gv[o0]; *(float4*)&sgv[4] = *(const float4*)&s_gv[o0+4];
    *(float4*)&bgv[0] = *(const float4*)&b_gv[o0]; *(float4*)&bgv[4] = *(const float4*)&b_gv[o0+4];

#pragma unroll
    for (int kk = 0; kk < 2; kk++) {
        const int nl = nl0 + kk;
        const int bn = b*N_ + n0 + nl;
        const float x0 = xs[nl*3], x1 = xs[nl*3+1], x2 = xs[nl*3+2];
        float qv[8], rv[8];
#pragma unroll
        for (int oo = 0; oo < 8; oo++) {
            const int o = o0 + oo;
            qv[oo] = x0*wgu[o*6+0] + x1*wgu[o*6+1] + x2*wgu[o*6+2];
            rv[oo] = x0*wgu[o*6+3] + x1*wgu[o*6+4] + x2*wgu[o*6+5];
        }
        float qs[8];
#pragma unroll
        for (int oo = 0; oo < 8; oo++) qs[oo] = qv[oo]*sgu[oo] + bgu[oo];
        *(float4*)&Qs[bn*128 + o0]     = *(float4*)&qs[0];
        *(float4*)&Qs[bn*128 + o0 + 4] = *(float4*)&qs[4];
        uint4 pk;
        pk.x = bf_pk(rv[0]*sgu[0], rv[1]*sgu[1]);
        pk.y = bf_pk(rv[2]*sgu[2], rv[3]*sgu[3]);
        pk.z = bf_pk(rv[4]*sgu[4], rv[5]*sgu[5]);
        pk.w = bf_pk(rv[6]*sgu[6], rv[7]*sgu[7]);
        *(uint4*)&Pcat[bn*128 + o0] = pk;

#pragma unroll
        for (int oo = 0; oo < 8; oo++) qs[oo] = acc[kk][oo]*sgv[oo] + bgv[oo];
        *(float4*)&Qs[bn*128 + 64 + o0]     = *(float4*)&qs[0];
        *(float4*)&Qs[bn*128 + 64 + o0 + 4] = *(float4*)&qs[4];
        pk.x = bf_pk(acc[kk][0]*sgv[0], acc[kk][1]*sgv[1]);
        pk.y = bf_pk(acc[kk][2]*sgv[2], acc[kk][3]*sgv[3]);
        pk.z = bf_pk(acc[kk][4]*sgv[4], acc[kk][5]*sgv[5]);
        pk.w = bf_pk(acc[kk][6]*sgv[6], acc[kk][7]*sgv[7]);
        *(uint4*)&Pcat[bn*128 + 64 + o0] = pk;
    }
}

// ---------------------------------------------------------------------------
// Kernel 2: MFMA main. Block = 256 thr (4 waves), PPB points each.
//  Per point: build fuse[32 k][128 i] bf16 in LDS (stride 65 words, <=2-way),
//  then wave w computes h[:, w*32..w*32+32) via 8x mfma_f32_32x32x16_bf16
//  with B-fragments of W_h resident in registers; relu+mean-pool over k via
//  16-reg sum + shfl_xor(32); write Pool[bn][o] (sum; /K in k_post).
// ---------------------------------------------------------------------------
__global__ __launch_bounds__(256) void k_main(
    const int*    __restrict__ idx,
    const float*  __restrict__ Qs,
    const ushort_t* __restrict__ Pcat,
    const ushort_t* __restrict__ Bpack,
    const float*  __restrict__ s_h, const float* __restrict__ b_h,
    float* __restrict__ Pool)
{
    const int t    = threadIdx.x;
    const int w    = t >> 6;
    const int lane = t & 63;
    const int m    = lane & 31;
    const int hh   = lane >> 5;

    __shared__ uint_t fuse[32 * 65];   // row k: words [k*65 .. k*65+64); bf16 pairs

    short8 Bf[8];
#pragma unroll
    for (int c = 0; c < 8; c++)
        Bf[c] = *(const short8*)&Bpack[((w*8 + c)*64 + lane)*8];

    const int o = w*32 + m;
    const float sh = s_h[o], bh = b_h[o];
    const int i0 = lane * 2;

    for (int p = 0; p < PPB; p++) {
        const int bn   = blockIdx.x * PPB + p;
        const int n    = bn & (N_ - 1);
        const int base = bn - n;                       // b*N_
        const int jall = idx[n*K_ + m];                // lane's row-j (dup in halves)
        const float2 q2 = *(const float2*)&Qs[bn*128 + i0];

        __syncthreads();   // prev point's fuse fully consumed
#pragma unroll
        for (int it = 0; it < 8; it++) {
            const int row = it*4 + w;
            const int j   = __shfl(jall, row);
            const uint_t rp = *(const uint_t*)&Pcat[(base + j)*128 + i0];
            const float v0 = fmaxf(q2.x + bf_lo(rp), 0.f);
            const float v1 = fmaxf(q2.y + bf_hi(rp), 0.f);
            fuse[row*65 + lane] = bf_pk(v0, v1);       // bank = (row+lane)%32: 2-way
        }
        __syncthreads();

        floatx16 acc = {};
#pragma unroll
        for (int c = 0; c < 8; c++) {
            const int wb = m*65 + c*8 + hh*4;          // bank = (m + ..)%32: 2-way
            union { uint_t u[4]; short8 s; } av;
            av.u[0] = fuse[wb+0]; av.u[1] = fuse[wb+1];
            av.u[2] = fuse[wb+2]; av.u[3] = fuse[wb+3];
            acc = __builtin_amdgcn_mfma_f32_32x32x16_bf16(av.s, Bf[c], acc, 0, 0, 0);
        }

        float v = 0.f;
#pragma unroll
        for (int r = 0; r < 16; r++)
            v += fmaxf(acc[r]*sh + bh, 0.f);
        v += __shfl_xor(v, 32);                        // rows +4 partner half
        if (hh == 0) Pool[bn*128 + o] = v;
    }
}

// ---------------------------------------------------------------------------
// Kernel 3: f layer + residual + transposed store.
//  out[b][c][n] = relu((Pool[bn]/K · W_f[c]) * s_f + b_f) + features[b][c][n]
// ---------------------------------------------------------------------------
__global__ __launch_bounds__(256) void k_post(
    const float* __restrict__ Pool,
    const float* __restrict__ W_fT,
    const float* __restrict__ s_f, const float* __restrict__ b_f,
    const float* __restrict__ features,
    float* __restrict__ outF)
{
    const int b   = blockIdx.x >> 6;
    const int n0  = (blockIdx.x & 63) * 64;
    const int t   = threadIdx.x;
    const int bn0 = b*N_ + n0;

    __shared__ float pt[64 * 129];

    for (int e = t; e < 64*128; e += 256) {
        int row = e >> 7, col = e & 127;
        pt[row*129 + col] = Pool[(bn0 + row)*128 + col];
    }
    __syncthreads();

    const int nt = t & 31, ct = t >> 5;
    const int nl0 = nt * 2, c0 = ct * 8;

    float acc[2][8] = {};
    for (int i = 0; i < 128; i++) {
        float p0 = pt[nl0*129 + i];
        float p1 = pt[nl0*129 + 129 + i];
        float wv[8];
        *(float4*)&wv[0] = *(const float4*)&W_fT[i*64 + c0];
        *(float4*)&wv[4] = *(const float4*)&W_fT[i*64 + c0 + 4];
#pragma unroll
        for (int oo = 0; oo < 8; oo++) {
            acc[0][oo] = fmaf(p0, wv[oo], acc[0][oo]);
            acc[1][oo] = fmaf(p1, wv[oo], acc[1][oo]);
        }
    }
    float sf[8], bfv[8];
    *(float4*)&sf[0]  = *(const float4*)&s_f[c0]; *(float4*)&sf[4]  = *(const float4*)&s_f[c0+4];
    *(float4*)&bfv[0] = *(const float4*)&b_f[c0]; *(float4*)&bfv[4] = *(const float4*)&b_f[c0+4];
#pragma unroll
    for (int oo = 0; oo < 8; oo++) {
        const int c = c0 + oo;
        const float2 fr = *(const float2*)&features[(b*C_ + c)*N_ + n0 + nl0];
        float2 ov;
        ov.x = fmaxf(acc[0][oo]*(1.f/(float)K_)*sf[oo] + bfv[oo], 0.f) + fr.x;
        ov.y = fmaxf(acc[1][oo]*(1.f/(float)K_)*sf[oo] + bfv[oo], 0.f) + fr.y;
        *(float2*)&outF[(b*C_ + c)*N_ + n0 + nl0] = ov;
    }
}

// ---------------------------------------------------------------------------
extern "C" void kernel_launch(void* const* d_in, const int* in_sizes, int n_in,
                              void* d_out, int out_size, void* d_ws, size_t ws_size,
                              hipStream_t stream)
{
    const float* xyz      = (const float*)d_in[0];
    const float* features = (const float*)d_in[1];
    const int*   idx      = (const int*)  d_in[2];
    const float* W_gu     = (const float*)d_in[3];
    const float* s_gu     = (const float*)d_in[4];
    const float* b_gu     = (const float*)d_in[5];
    const float* W_gv     = (const float*)d_in[6];
    const float* s_gv     = (const float*)d_in[7];
    const float* b_gv     = (const float*)d_in[8];
    const float* W_h      = (const float*)d_in[9];
    const float* s_h      = (const float*)d_in[10];
    const float* b_h      = (const float*)d_in[11];
    const float* W_f      = (const float*)d_in[12];
    const float* s_f      = (const float*)d_in[13];
    const float* b_f      = (const float*)d_in[14];

    float* out  = (float*)d_out;          // tuple: xyz first, then out
    float* outF = out + B_*N_*3;

    // workspace carve (~20.1 MB)
    char* wp = (char*)d_ws;
    float*    Qs    = (float*)wp;    wp += (size_t)B_*N_*128*4;   // 8 MB
    float*    Pool  = (float*)wp;    wp += (size_t)B_*N_*128*4;   // 8 MB
    ushort_t* Pcat  = (ushort_t*)wp; wp += (size_t)B_*N_*128*2;   // 4 MB
    float*    W_gvT = (float*)wp;    wp += D2_*C_*4;
    ushort_t* Bpack = (ushort_t*)wp; wp += DH_*(D1_+D2_)*2;
    float*    W_fT  = (float*)wp;    wp += C_*DH_*4;

    k_transforms<<<304, 256, 0, stream>>>(xyz, W_gv, W_h, W_f, out, W_gvT, Bpack, W_fT);
    k_pre<<<B_*(N_/64), 256, 0, stream>>>(xyz, features, W_gvT, W_gu,
                                          s_gu, b_gu, s_gv, b_gv, Qs, Pcat);
    k_main<<<(B_*N_)/PPB, 256, 0, stream>>>(idx, Qs, Pcat, Bpack, s_h, b_h, Pool);
    k_post<<<B_*(N_/64), 256, 0, stream>>>(Pool, W_fT, s_f, b_f, features, outF);
}